// Round 1
// baseline (87.483 us; speedup 1.0000x reference)
//
#include <hip/hip_runtime.h>
#include <hip/hip_bf16.h>

// out[b][s] = | prod_{k<4} cos((x[b][k] - sv[s][k]) * 0.5) |
// B = S = 4096, K = 4, fp32.
// Memory-bound on the 64 MiB output write. One block per b-row; each thread
// produces 4 consecutive s-outputs and stores one float4.

__global__ __launch_bounds__(256) void quantum_kernel(
    const float4* __restrict__ x,    // [B] float4 (K=4)
    const float4* __restrict__ sv,   // [S] float4
    float4* __restrict__ out,        // [B][S/4]
    int s_quads)                     // S/4
{
    const int b  = blockIdx.y;
    const int q  = blockIdx.x * blockDim.x + threadIdx.x;  // which output quad
    if (q >= s_quads) return;

    const float4 xb = x[b];  // broadcast across the block (L1 hit)

    float4 r;
    float* rp = &r.x;
#pragma unroll
    for (int i = 0; i < 4; ++i) {
        const float4 s = sv[(size_t)4 * q + i];
        float p = __cosf((xb.x - s.x) * 0.5f)
                * __cosf((xb.y - s.y) * 0.5f)
                * __cosf((xb.z - s.z) * 0.5f)
                * __cosf((xb.w - s.w) * 0.5f);
        rp[i] = fabsf(p);
    }
    out[(size_t)b * s_quads + q] = r;
}

extern "C" void kernel_launch(void* const* d_in, const int* in_sizes, int n_in,
                              void* d_out, int out_size, void* d_ws, size_t ws_size,
                              hipStream_t stream) {
    const float4* x  = (const float4*)d_in[0];   // [B,4] fp32
    const float4* sv = (const float4*)d_in[1];   // [S,4] fp32
    float4* out = (float4*)d_out;                // [B,S] fp32

    const int B = in_sizes[0] / 4;
    const int S = in_sizes[1] / 4;
    const int s_quads = S / 4;                   // 1024 for S=4096

    const int block = 256;
    dim3 grid((s_quads + block - 1) / block, B); // (4, 4096)
    quantum_kernel<<<grid, block, 0, stream>>>(x, sv, out, s_quads);
}